// Round 5
// baseline (699.539 us; speedup 1.0000x reference)
//
#include <hip/hip_runtime.h>

// ExtractSearchWindows: out[b,h,w,rr,tt] = (uint8)Q[b, h+off+ry+ty, w+off+rx+tx],
// Q = input padded by 6; stored as INT32.
//
// R12 theory: esw is pinned at ~240us = 2x the 112us write roofline across six
// structural variants (R3-R11). The only arithmetic that reproduces 2x: every
// output 128B line is fetched from HBM once before being written (L2
// write-allocate on partial-line store miss). Group bases are 9604*g ints ==
// 16*(4g mod 32)B into a line -> NEVER 128B-aligned -> every 1KB wave store
// spans 7 full + 2 partial lines; if consecutive instructions' halves don't
// merge before allocate, every line fetches: 708MB extra read -> 225us ~= the
// measured ~240. Fill is fast because fillBufferAligned stores whole lines
// (its FETCH_SIZE ~= 0 proves aligned stores don't fetch). Fix: per-group
// head/middle/tail split. Head to the next 128B boundary is always a whole
// number of quads (9604g mod 32 ints = 4g mod 32 -> multiple of 4 ints, <=7
// quads). Middle = 64-quad rounds, every 1KB store exactly 8 full lines;
// remainder is a multiple of 8 quads (full lines); tail <=7 quads. Only ~2
// boundary lines/group stay partial (2.4MB chip-wide). Structure otherwise
// R11-identical: wave-private swizzled patch, zero s_barrier, L2-hot offset
// table prefetched one round ahead, stores never awaited.

#define KT 7
#define K2 49
#define MAX_SR 3
#define B_ 2
#define H_ 192
#define W_ 192
#define HW (H_ * W_)
#define PAD 6
#define NT 256
#define NBLOCKS 512
#define WPB (NT / 64)                 // 4 waves per block
#define NWAVES (NBLOCKS * WPB)        // 2048; 18432 groups / 2048 = 9 per wave
#define PS 17                         // patch row stride in element space
#define BUFI 280                      // swz(219)=273 -> pad to 280 ints
#define NGROUPS (B_ * H_ * W_ / 4)    // 18432
#define TABQ 2560                     // quads covered by table (>= 2439 used)
#define TABN (4 * TABQ)               // 10240 ints

typedef int vint4 __attribute__((ext_vector_type(4)));

__device__ __forceinline__ int swz(int e) { return e + (e >> 2); }  // bijective

__device__ __forceinline__ int tab_entry(int jj, int cv, int offset, int d,
                                         int cvmagic) {
    if (jj >= 4 * d) jj = 4 * d - 1;            // clamp inactive tail
    int p_in = (jj >= d) + (jj >= 2 * d) + (jj >= 3 * d);
    int j  = jj - p_in * d;
    int rr = j / K2;                            // const divisor 49
    int tt = j - rr * K2;
    int ry = (rr * cvmagic) >> 16;              // rr / cv  (rr < 49)
    int rx = rr - ry * cv;
    int ty = tt / KT;                           // const divisor 7
    int tx = tt - ty * KT;
    int e = (offset + ry + ty) * PS + (offset + rx + tx) + p_in;
    return 4 * swz(e);                          // swizzled byte offset
}

__global__ __launch_bounds__(256) void tab_kernel(
    int* __restrict__ tab, int cv, int offset, int d, int cvmagic)
{
    int jj = blockIdx.x * 256 + threadIdx.x;
    if (jj < TABN) tab[jj] = tab_entry(jj, cv, offset, d, cvmagic);
}

__global__ __launch_bounds__(NT, 2) void esw_kernel(
    const float* __restrict__ in, int* __restrict__ out,
    const int* __restrict__ tab,
    int cv, int offset, int d, int cvmagic)
{
    __shared__ int patch[WPB][BUFI];

    const int tid  = threadIdx.x;
    const int lane = tid & 63;
    const int wv   = tid >> 6;
    int* const pbuf = patch[wv];                 // wave-private patch
    const char* const pb = (const char*)pbuf;

    const int wid = blockIdx.x * WPB + wv;

    for (int g = wid; g < NGROUPS; g += NWAVES) {
        // ---- stage the 13x16 neighborhood of this group's 4 pixels ----
        const int pix0 = 4 * g;                  // W%4==0 -> group in one row
        const int b   = pix0 / HW;
        const int rem = pix0 - b * HW;
        const int h   = rem / W_;
        const int w   = rem - h * W_;
        #pragma unroll
        for (int k = 0; k < 4; ++k) {
            int e = lane + 64 * k;               // k<3 full; k==3: lanes<16
            if (e < 13 * 16) {
                int dy = e >> 4, dx = e & 15;
                int y = h + dy - PAD, x = w + dx - PAD;
                int v = 0;
                if ((unsigned)y < (unsigned)H_ && (unsigned)x < (unsigned)W_)
                    v = (int)in[b * HW + y * W_ + x];
                pbuf[swz(dy * PS + dx)] = v;
            }
        }
        asm volatile("s_waitcnt lgkmcnt(0)" ::: "memory");  // patch ready
        // No s_barrier anywhere — patch is wave-private.

        // ---- 128B-aligned store grid for this group ----
        // base quad = d*g ; d==1 (mod 8) for all valid cv, so base%8 = g%8.
        int* op = out + g * (4 * d);             // <=177M ints, 32-bit safe
        const int hq = (8 - (g & 7)) & 7;        // head quads to 128B boundary
        const int tq = (d - hq) & 7;             // tail quads after aligned mid
        const int M  = d - hq - tq;              // middle quads, %64-friendly
        const int R  = M >> 6;                   // full 64-quad rounds
        const int rq = M & 63;                   // remainder quads (mult of 8)

        if (tab) {
            // head + tail fragments (few lanes; partial boundary lines only)
            if (lane < hq) {
                vint4 t0 = *(const vint4*)(tab + 4 * lane);
                vint4 v;
                v.x = *(const int*)(pb + t0.x);
                v.y = *(const int*)(pb + t0.y);
                v.z = *(const int*)(pb + t0.z);
                v.w = *(const int*)(pb + t0.w);
                *(vint4*)(op + 4 * lane) = v;
            }
            if (lane < tq) {
                int q = d - tq + lane;
                vint4 t1 = *(const vint4*)(tab + 4 * q);
                vint4 v;
                v.x = *(const int*)(pb + t1.x);
                v.y = *(const int*)(pb + t1.y);
                v.z = *(const int*)(pb + t1.z);
                v.w = *(const int*)(pb + t1.w);
                *(vint4*)(op + 4 * q) = v;
            }
            // aligned middle: every 1KB store covers exactly 8 full lines
            const int* tb = tab + 4 * (hq + lane);
            vint4 t = *(const vint4*)tb;                 // round 0
            for (int r = 0; r < R; ++r) {
                vint4 tn = *(const vint4*)(tb + 256 * (r + 1));  // prefetch
                int q = hq + 64 * r + lane;
                vint4 v;
                v.x = *(const int*)(pb + t.x);
                v.y = *(const int*)(pb + t.y);
                v.z = *(const int*)(pb + t.z);
                v.w = *(const int*)(pb + t.w);
                *(vint4*)(op + 4 * q) = v;
                t = tn;
            }
            if (lane < rq) {                     // aligned remainder (full lines)
                int q = hq + 64 * R + lane;      // uses final prefetched t
                vint4 v;
                v.x = *(const int*)(pb + t.x);
                v.y = *(const int*)(pb + t.y);
                v.z = *(const int*)(pb + t.z);
                v.w = *(const int*)(pb + t.w);
                *(vint4*)(op + 4 * q) = v;
            }
        } else {                                 // no-workspace fallback
            for (int q = lane; q < d; q += 64) {
                vint4 v;
                v.x = *(const int*)(pb + tab_entry(4 * q + 0, cv, offset, d, cvmagic));
                v.y = *(const int*)(pb + tab_entry(4 * q + 1, cv, offset, d, cvmagic));
                v.z = *(const int*)(pb + tab_entry(4 * q + 2, cv, offset, d, cvmagic));
                v.w = *(const int*)(pb + tab_entry(4 * q + 3, cv, offset, d, cvmagic));
                *(vint4*)(op + 4 * q) = v;
            }
        }
        // Order next group's stage ds_writes behind this group's gather reads.
        asm volatile("s_waitcnt lgkmcnt(0)" ::: "memory");
    }
}

extern "C" void kernel_launch(void* const* d_in, const int* in_sizes, int n_in,
                              void* d_out, int out_size, void* d_ws, size_t ws_size,
                              hipStream_t stream) {
    const float* in = (const float*)d_in[0];
    int* out = (int*)d_out;

    // out_size = B*H*W * cv^2 * 49
    int cv2 = out_size / (B_ * H_ * W_ * K2);
    int cv = 1;
    while (cv * cv < cv2) ++cv;
    int offset = MAX_SR - (cv - 1) / 2;
    int d = cv2 * K2;
    int cvmagic = 65536 / cv + 1;

    int* tab = (ws_size >= (size_t)(TABN * sizeof(int))) ? (int*)d_ws : nullptr;
    if (tab)
        tab_kernel<<<(TABN + 255) / 256, 256, 0, stream>>>(tab, cv, offset, d,
                                                           cvmagic);
    esw_kernel<<<NBLOCKS, NT, 0, stream>>>(in, out, tab, cv, offset, d, cvmagic);
}